// Round 1
// baseline (4705.427 us; speedup 1.0000x reference)
//
#include <hip/hip_runtime.h>
#include <hip/hip_bf16.h>

#define BATCH 64
#define NPIX 196
#define ENCD 2048
#define ATTD 512
#define DECD 512
#define EMBD 512
#define NVOCAB 10000
#define TSTEPS 24
#define KX 3072   // EMB + ENC + DEC

// ---------------- meta: captions + decode_lengths as floats ----------------
__global__ void k_meta(const int* __restrict__ caps, const int* __restrict__ lens,
                       float* __restrict__ cap_out, float* __restrict__ len_out) {
    int i = blockIdx.x * 256 + threadIdx.x;
    if (i < BATCH * 25) cap_out[i] = (float)caps[i];
    if (i < BATCH)      len_out[i] = (float)(lens[i] - 1);
}

// ---------------- mean over 196 positions ----------------
__global__ void k_mean(const float* __restrict__ enc, float* __restrict__ mean_enc) {
    int b = blockIdx.x;
    int e = blockIdx.y * 256 + threadIdx.x;
    const float* base = enc + (size_t)b * NPIX * ENCD + e;
    float s = 0.f;
    for (int p = 0; p < NPIX; ++p) s += base[(size_t)p * ENCD];
    mean_enc[(size_t)b * ENCD + e] = s * (1.0f / NPIX);
}

// ---------------- h0/c0 init: 4 batch rows per block ----------------
__global__ __launch_bounds__(256) void k_init_hc(
        const float* __restrict__ mean_enc,
        const float* __restrict__ Wh, const float* __restrict__ bh,
        const float* __restrict__ Wc, const float* __restrict__ bc,
        float* __restrict__ h, float* __restrict__ c) {
    __shared__ float m[4][ENCD];
    int bg = blockIdx.x * 4;
    for (int i = threadIdx.x; i < 4 * ENCD; i += 256)
        m[i >> 11][i & 2047] = mean_enc[(size_t)(bg + (i >> 11)) * ENCD + (i & 2047)];
    __syncthreads();
    int j = blockIdx.y * 256 + threadIdx.x;   // 0..1023
    const float* W; const float* bias; float* dst; int col;
    if (j < DECD) { W = Wh; bias = bh; dst = h; col = j; }
    else          { W = Wc; bias = bc; dst = c; col = j - DECD; }
    float acc[4] = {0.f, 0.f, 0.f, 0.f};
    for (int k = 0; k < ENCD; ++k) {
        float w = W[(size_t)k * DECD + col];
#pragma unroll
        for (int q = 0; q < 4; ++q) acc[q] += m[q][k] * w;
    }
#pragma unroll
    for (int q = 0; q < 4; ++q) dst[(size_t)(bg + q) * DECD + col] = acc[q] + bias[col];
}

// ---------------- transpose W_ih / W_hh into combined WT (3072 x 2048) ----------------
__global__ void k_transpose(const float* __restrict__ Wih, const float* __restrict__ Whh,
                            float* __restrict__ WT) {
    __shared__ float tile[32][33];
    int jb = blockIdx.x * 32;   // output col (j, 0..2047)
    int kb = blockIdx.y * 32;   // output row (k, 0..3071)
    int tx = threadIdx.x & 31, ty = threadIdx.x >> 5;  // 32 x 8
    for (int i = 0; i < 32; i += 8) {
        int j = jb + ty + i, k = kb + tx;
        float v;
        if (k < 2560) v = Wih[(size_t)j * 2560 + k];
        else          v = Whh[(size_t)j * 512 + (k - 2560)];
        tile[ty + i][tx] = v;
    }
    __syncthreads();
    for (int i = 0; i < 32; i += 8)
        WT[(size_t)(kb + ty + i) * 2048 + jb + tx] = tile[tx][ty + i];
}

// ---------------- generic 64x64-tile fp32 GEMM: C[z] = A @ W (+bias) ----------------
// A: MxK row-major (ldA), W: KxN row-major (k-major, coalesced on n).
// blockIdx.z selects K-chunk; partial written to C + z*M*N. bias only if non-null.
__global__ __launch_bounds__(256) void k_gemm64(
        const float* __restrict__ A, const float* __restrict__ W,
        const float* __restrict__ bias, float* __restrict__ C,
        int K, int N, int ldA, int kChunk) {
    __shared__ float As[32][68];
    __shared__ float Ws[32][68];
    int m0 = blockIdx.x * 64, n0 = blockIdx.y * 64;
    int k0 = blockIdx.z * kChunk, k1 = k0 + kChunk;
    int tid = threadIdx.x;
    int tc = tid & 15, tr = tid >> 4;
    float acc[4][4] = {};
    for (int kt = k0; kt < k1; kt += 32) {
        {
            int kk = tid & 31, mi = tid >> 5;
#pragma unroll
            for (int i = 0; i < 8; ++i)
                As[kk][mi + i * 8] = A[(size_t)(m0 + mi + i * 8) * ldA + kt + kk];
        }
        {
            int nn = tid & 63, kk = tid >> 6;
#pragma unroll
            for (int i = 0; i < 8; ++i)
                Ws[kk + i * 4][nn] = W[(size_t)(kt + kk + i * 4) * N + n0 + nn];
        }
        __syncthreads();
#pragma unroll
        for (int kk = 0; kk < 32; ++kk) {
            float4 a = *reinterpret_cast<const float4*>(&As[kk][tr * 4]);
            float4 w = *reinterpret_cast<const float4*>(&Ws[kk][tc * 4]);
            float av[4] = {a.x, a.y, a.z, a.w};
            float wv[4] = {w.x, w.y, w.z, w.w};
#pragma unroll
            for (int i = 0; i < 4; ++i)
#pragma unroll
                for (int j = 0; j < 4; ++j) acc[i][j] += av[i] * wv[j];
        }
        __syncthreads();
    }
    size_t M = (size_t)gridDim.x * 64;
    float* Cz = C + (size_t)blockIdx.z * M * N;
#pragma unroll
    for (int i = 0; i < 4; ++i) {
        int m = m0 + tr * 4 + i;
#pragma unroll
        for (int j = 0; j < 4; ++j) {
            int n = n0 + tc * 4 + j;
            float v = acc[i][j];
            if (bias) v += bias[n];
            Cz[(size_t)m * N + n] = v;
        }
    }
}

// ---------------- per-step: att2 + forget-gate beta, 8 batch rows / block ----------------
__global__ __launch_bounds__(256) void k_pre(
        const float* __restrict__ h,
        const float* __restrict__ Wd, const float* __restrict__ bd,
        const float* __restrict__ Wfb, const float* __restrict__ bfb,
        float* __restrict__ att2, float* __restrict__ gate) {
    __shared__ float hr[8][DECD];
    int bg = blockIdx.x * 8;
    for (int i = threadIdx.x; i < 8 * DECD; i += 256)
        hr[i >> 9][i & 511] = h[(size_t)(bg + (i >> 9)) * DECD + (i & 511)];
    __syncthreads();
    int j = blockIdx.y * 256 + threadIdx.x;   // 0..2559
    float acc[8] = {};
    if (j < ATTD) {
        for (int k = 0; k < DECD; ++k) {
            float w = Wd[(size_t)k * ATTD + j];
#pragma unroll
            for (int q = 0; q < 8; ++q) acc[q] += hr[q][k] * w;
        }
#pragma unroll
        for (int q = 0; q < 8; ++q) att2[(size_t)(bg + q) * ATTD + j] = acc[q] + bd[j];
    } else {
        int e = j - ATTD;
        for (int k = 0; k < DECD; ++k) {
            float w = Wfb[(size_t)k * ENCD + e];
#pragma unroll
            for (int q = 0; q < 8; ++q) acc[q] += hr[q][k] * w;
        }
#pragma unroll
        for (int q = 0; q < 8; ++q)
            gate[(size_t)(bg + q) * ENCD + e] = 1.f / (1.f + __expf(-(acc[q] + bfb[e])));
    }
}

// ---------------- per-step: attention scores + softmax ----------------
__global__ __launch_bounds__(256) void k_attsm(
        const float* __restrict__ att1, const float* __restrict__ att2,
        const float* __restrict__ v_att, const float* __restrict__ bv,
        const int* __restrict__ lens,
        float* __restrict__ alpha_ws, float* __restrict__ alpha_out, int t) {
    int b = blockIdx.x;
    __shared__ float a2[ATTD];
    __shared__ float vv[ATTD];
    __shared__ float ev[NPIX];
    __shared__ float red[1];
    int tid = threadIdx.x;
    for (int k = tid; k < ATTD; k += 256) {
        a2[k] = att2[(size_t)b * ATTD + k];
        vv[k] = v_att[k];
    }
    __syncthreads();
    int wid = tid >> 6, lane = tid & 63;
    for (int p = wid; p < NPIX; p += 4) {
        const float* r = att1 + ((size_t)b * NPIX + p) * ATTD;
        float s = 0.f;
        for (int k = lane; k < ATTD; k += 64)
            s += fmaxf(r[k] + a2[k], 0.f) * vv[k];
        for (int off = 32; off > 0; off >>= 1) s += __shfl_down(s, off);
        if (lane == 0) ev[p] = s + bv[0];
    }
    __syncthreads();
    if (wid == 0) {
        float m = -1e30f;
        for (int p = lane; p < NPIX; p += 64) m = fmaxf(m, ev[p]);
        for (int off = 32; off > 0; off >>= 1) m = fmaxf(m, __shfl_down(m, off));
        m = __shfl(m, 0);
        float s = 0.f;
        for (int p = lane; p < NPIX; p += 64) {
            float ex = __expf(ev[p] - m);
            ev[p] = ex;
            s += ex;
        }
        for (int off = 32; off > 0; off >>= 1) s += __shfl_down(s, off);
        if (lane == 0) red[0] = 1.0f / s;
    }
    __syncthreads();
    float inv = red[0];
    bool active = t < (lens[b] - 1);
    for (int p = tid; p < NPIX; p += 256) {
        float a = ev[p] * inv;
        alpha_ws[(size_t)b * NPIX + p] = a;
        alpha_out[((size_t)b * TSTEPS + t) * NPIX + p] = active ? a : 0.f;
    }
}

// ---------------- per-step: context (alpha @ enc) * gate, and build X = [emb, ctx, h] ----------------
__global__ __launch_bounds__(256) void k_ctx_x(
        const float* __restrict__ enc, const float* __restrict__ alpha,
        const float* __restrict__ gate, const float* __restrict__ h,
        const float* __restrict__ emb, const int* __restrict__ caps,
        float* __restrict__ X, int t) {
    __shared__ float al[NPIX];
    int b = blockIdx.x;
    int tid = threadIdx.x;
    for (int p = tid; p < NPIX; p += 256) al[p] = alpha[(size_t)b * NPIX + p];
    __syncthreads();
    int j = blockIdx.y * 256 + tid;   // 0..3071
    float val;
    if (j < EMBD) {
        int tok = caps[b * 25 + t];
        val = emb[(size_t)tok * EMBD + j];
    } else if (j < EMBD + ENCD) {
        int e = j - EMBD;
        const float* base = enc + (size_t)b * NPIX * ENCD + e;
        float s = 0.f;
        for (int p = 0; p < NPIX; ++p) s += al[p] * base[(size_t)p * ENCD];
        val = s * gate[(size_t)b * ENCD + e];
    } else {
        val = h[(size_t)b * DECD + (j - EMBD - ENCD)];
    }
    X[(size_t)b * KX + j] = val;
}

// ---------------- per-step: LSTM pointwise (sum K-split partials, update h/c) ----------------
__global__ __launch_bounds__(256) void k_pw(
        const float* __restrict__ gpart,
        const float* __restrict__ b_ih, const float* __restrict__ b_hh,
        const int* __restrict__ lens,
        float* __restrict__ h, float* __restrict__ c, int t) {
    int idx = blockIdx.x * 256 + threadIdx.x;   // 0..32767
    int b = idx >> 9, d = idx & 511;
    float gi = 0.f, gf = 0.f, gg = 0.f, go = 0.f;
#pragma unroll
    for (int z = 0; z < 4; ++z) {
        const float* gp = gpart + (size_t)z * BATCH * 2048 + (size_t)b * 2048;
        gi += gp[d];
        gf += gp[512 + d];
        gg += gp[1024 + d];
        go += gp[1536 + d];
    }
    gi += b_ih[d] + b_hh[d];
    gf += b_ih[512 + d] + b_hh[512 + d];
    gg += b_ih[1024 + d] + b_hh[1024 + d];
    go += b_ih[1536 + d] + b_hh[1536 + d];
    float cc = c[idx];
    float si = 1.f / (1.f + __expf(-gi));
    float sf = 1.f / (1.f + __expf(-gf));
    float so = 1.f / (1.f + __expf(-go));
    float cn = sf * cc + si * tanhf(gg);
    float hn = so * tanhf(cn);
    if (t < lens[b] - 1) { c[idx] = cn; h[idx] = hn; }
}

// ---------------- per-step: vocab projection (masked) ----------------
__global__ __launch_bounds__(256) void k_predk(
        const float* __restrict__ h, const float* __restrict__ Wfc,
        const float* __restrict__ bfc, const int* __restrict__ lens,
        float* __restrict__ pred, int t) {
    __shared__ float As[32][68];
    __shared__ float Ws[32][68];
    int n0 = blockIdx.y * 64;
    int tid = threadIdx.x, tc = tid & 15, tr = tid >> 4;
    float acc[4][4] = {};
    for (int kt = 0; kt < 512; kt += 32) {
        {
            int kk = tid & 31, mi = tid >> 5;
#pragma unroll
            for (int i = 0; i < 8; ++i)
                As[kk][mi + i * 8] = h[(size_t)(mi + i * 8) * 512 + kt + kk];
        }
        {
            int nn = tid & 63, kk = tid >> 6;
            int n = n0 + nn;
#pragma unroll
            for (int i = 0; i < 8; ++i)
                Ws[kk + i * 4][nn] = (n < NVOCAB) ? Wfc[(size_t)(kt + kk + i * 4) * NVOCAB + n] : 0.f;
        }
        __syncthreads();
#pragma unroll
        for (int kk = 0; kk < 32; ++kk) {
            float4 a = *reinterpret_cast<const float4*>(&As[kk][tr * 4]);
            float4 w = *reinterpret_cast<const float4*>(&Ws[kk][tc * 4]);
            float av[4] = {a.x, a.y, a.z, a.w};
            float wv[4] = {w.x, w.y, w.z, w.w};
#pragma unroll
            for (int i = 0; i < 4; ++i)
#pragma unroll
                for (int j = 0; j < 4; ++j) acc[i][j] += av[i] * wv[j];
        }
        __syncthreads();
    }
#pragma unroll
    for (int i = 0; i < 4; ++i) {
        int b = tr * 4 + i;
        bool active = t < (lens[b] - 1);
#pragma unroll
        for (int j = 0; j < 4; ++j) {
            int n = n0 + tc * 4 + j;
            if (n < NVOCAB)
                pred[((size_t)b * TSTEPS + t) * NVOCAB + n] = active ? (acc[i][j] + bfc[n]) : 0.f;
        }
    }
}

extern "C" void kernel_launch(void* const* d_in, const int* in_sizes, int n_in,
                              void* d_out, int out_size, void* d_ws, size_t ws_size,
                              hipStream_t stream) {
    const float* enc  = (const float*)d_in[0];
    const int*   caps = (const int*)d_in[1];
    const int*   lens = (const int*)d_in[2];
    const float* emb  = (const float*)d_in[3];
    const float* We   = (const float*)d_in[4];
    const float* be   = (const float*)d_in[5];
    const float* Wd   = (const float*)d_in[6];
    const float* bd   = (const float*)d_in[7];
    const float* vatt = (const float*)d_in[8];
    const float* bv   = (const float*)d_in[9];
    const float* Wih  = (const float*)d_in[10];
    const float* bih  = (const float*)d_in[11];
    const float* Whh  = (const float*)d_in[12];
    const float* bhh  = (const float*)d_in[13];
    const float* Winh = (const float*)d_in[14];
    const float* binh = (const float*)d_in[15];
    const float* Winc = (const float*)d_in[16];
    const float* binc = (const float*)d_in[17];
    const float* Wfb  = (const float*)d_in[18];
    const float* bfb  = (const float*)d_in[19];
    const float* Wfc  = (const float*)d_in[20];
    const float* bfc  = (const float*)d_in[21];

    float* out       = (float*)d_out;
    float* pred_out  = out;                         // 64*24*10000 = 15,360,000
    float* cap_out   = out + 15360000;              // 1600
    float* len_out   = out + 15361600;              // 64
    float* alpha_out = out + 15361664;              // 64*24*196

    float* ws       = (float*)d_ws;
    float* att1     = ws;                    // 6,422,528
    float* WT       = att1 + 6422528;        // 6,291,456
    float* mean_enc = WT + 6291456;          // 131,072
    float* h        = mean_enc + 131072;     // 32,768
    float* c        = h + 32768;             // 32,768
    float* att2     = c + 32768;             // 32,768
    float* gate     = att2 + 32768;          // 131,072
    float* alpha    = gate + 131072;         // 12,544
    float* X        = alpha + 12544;         // 196,608
    float* gpart    = X + 196608;            // 4 * 131,072

    k_meta<<<7, 256, 0, stream>>>(caps, lens, cap_out, len_out);
    k_mean<<<dim3(BATCH, 8), 256, 0, stream>>>(enc, mean_enc);
    k_init_hc<<<dim3(16, 4), 256, 0, stream>>>(mean_enc, Winh, binh, Winc, binc, h, c);
    k_transpose<<<dim3(64, 96), 256, 0, stream>>>(Wih, Whh, WT);
    // att1 = enc @ We_att + be_att   (12544 x 2048 @ 2048 x 512)
    k_gemm64<<<dim3(196, 8, 1), 256, 0, stream>>>(enc, We, be, att1, 2048, 512, 2048, 2048);

    for (int t = 0; t < TSTEPS; ++t) {
        k_pre<<<dim3(8, 10), 256, 0, stream>>>(h, Wd, bd, Wfb, bfb, att2, gate);
        k_attsm<<<BATCH, 256, 0, stream>>>(att1, att2, vatt, bv, lens, alpha, alpha_out, t);
        k_ctx_x<<<dim3(BATCH, 12), 256, 0, stream>>>(enc, alpha, gate, h, emb, caps, X, t);
        // gates partials: X(64x3072) @ WT(3072x2048), K split into 4
        k_gemm64<<<dim3(1, 32, 4), 256, 0, stream>>>(X, WT, nullptr, gpart, 3072, 2048, 3072, 768);
        k_pw<<<128, 256, 0, stream>>>(gpart, bih, bhh, lens, h, c, t);
        k_predk<<<dim3(1, 157), 256, 0, stream>>>(h, Wfc, bfc, lens, pred_out, t);
    }
}

// Round 2
// 2897.929 us; speedup vs baseline: 1.6237x; 1.6237x over previous
//
#include <hip/hip_runtime.h>
#include <hip/hip_bf16.h>

#define BATCH 64
#define NPIX 196
#define ENCD 2048
#define ATTD 512
#define DECD 512
#define EMBD 512
#define NVOCAB 10000
#define TSTEPS 24
#define KX 3072   // EMB + ENC + DEC

typedef short bf16x8 __attribute__((ext_vector_type(8)));
typedef float f32x4 __attribute__((ext_vector_type(4)));

__device__ inline ushort f2bf(float f) {
    union { float f; unsigned u; } v; v.f = f;
    unsigned r = (v.u + 0x7fff + ((v.u >> 16) & 1)) >> 16;
    return (ushort)r;
}
__device__ inline float bf2f(ushort u) {
    union { unsigned u; float f; } v; v.u = ((unsigned)u) << 16;
    return v.f;
}

// ---------------- meta: captions + decode_lengths as floats ----------------
__global__ void k_meta(const int* __restrict__ caps, const int* __restrict__ lens,
                       float* __restrict__ cap_out, float* __restrict__ len_out) {
    int i = blockIdx.x * 256 + threadIdx.x;
    if (i < BATCH * 25) cap_out[i] = (float)caps[i];
    if (i < BATCH)      len_out[i] = (float)(lens[i] - 1);
}

// ---------------- mean over 196 positions ----------------
__global__ void k_mean(const float* __restrict__ enc, float* __restrict__ mean_enc) {
    int b = blockIdx.x;
    int e = blockIdx.y * 256 + threadIdx.x;
    const float* base = enc + (size_t)b * NPIX * ENCD + e;
    float s = 0.f;
    for (int p = 0; p < NPIX; ++p) s += base[(size_t)p * ENCD];
    mean_enc[(size_t)b * ENCD + e] = s * (1.0f / NPIX);
}

// ---------------- h0/c0 init (h -> bf16, c -> fp32) ----------------
__global__ __launch_bounds__(256) void k_init_hc(
        const float* __restrict__ mean_enc,
        const float* __restrict__ Wh, const float* __restrict__ bh,
        const float* __restrict__ Wc, const float* __restrict__ bc,
        ushort* __restrict__ hbf, float* __restrict__ c) {
    __shared__ float m[4][ENCD];
    int bg = blockIdx.x * 4;
    for (int i = threadIdx.x; i < 4 * ENCD; i += 256)
        m[i >> 11][i & 2047] = mean_enc[(size_t)(bg + (i >> 11)) * ENCD + (i & 2047)];
    __syncthreads();
    int j = blockIdx.y * 256 + threadIdx.x;   // 0..1023
    const float* W; const float* bias; int col;
    bool isH = j < DECD;
    if (isH) { W = Wh; bias = bh; col = j; }
    else     { W = Wc; bias = bc; col = j - DECD; }
    float acc[4] = {0.f, 0.f, 0.f, 0.f};
    for (int k = 0; k < ENCD; ++k) {
        float w = W[(size_t)k * DECD + col];
#pragma unroll
        for (int q = 0; q < 4; ++q) acc[q] += m[q][k] * w;
    }
#pragma unroll
    for (int q = 0; q < 4; ++q) {
        float v = acc[q] + bias[col];
        if (isH) hbf[(size_t)(bg + q) * DECD + col] = f2bf(v);
        else     c[(size_t)(bg + q) * DECD + col] = v;
    }
}

// ---------------- one-time: WTj[j][k] bf16, j in original gate order ----------------
__global__ __launch_bounds__(256) void k_cp_wtj(const float* __restrict__ Wih,
                                                const float* __restrict__ Whh,
                                                ushort* __restrict__ WTj) {
    int j = blockIdx.x;
    for (int k = threadIdx.x; k < KX; k += 256) {
        float v = (k < 2560) ? Wih[(size_t)j * 2560 + k] : Whh[(size_t)j * 512 + (k - 2560)];
        WTj[(size_t)j * KX + k] = f2bf(v);
    }
}

// ---------------- one-time transposes to [n][k] bf16 ----------------
__global__ __launch_bounds__(256) void k_tr_bpre(const float* __restrict__ Wd,
                                                 const float* __restrict__ Wfb,
                                                 ushort* __restrict__ out) {
    __shared__ float tile[32][33];
    int nb = blockIdx.x * 32, kb = blockIdx.y * 32;
    int tx = threadIdx.x & 31, ty = threadIdx.x >> 5;
    for (int i = 0; i < 32; i += 8) {
        int k = kb + ty + i, n = nb + tx;
        float v = (n < ATTD) ? Wd[(size_t)k * ATTD + n] : Wfb[(size_t)k * ENCD + (n - ATTD)];
        tile[ty + i][tx] = v;
    }
    __syncthreads();
    for (int i = 0; i < 32; i += 8)
        out[(size_t)(nb + ty + i) * 512 + kb + tx] = f2bf(tile[tx][ty + i]);
}

__global__ __launch_bounds__(256) void k_tr_wfct(const float* __restrict__ Wfc,
                                                 ushort* __restrict__ out) {
    __shared__ float tile[32][33];
    int nb = blockIdx.x * 32, kb = blockIdx.y * 32;
    int tx = threadIdx.x & 31, ty = threadIdx.x >> 5;
    for (int i = 0; i < 32; i += 8) {
        int k = kb + ty + i, n = nb + tx;
        float v = (n < NVOCAB) ? Wfc[(size_t)k * NVOCAB + n] : 0.f;
        tile[ty + i][tx] = v;
    }
    __syncthreads();
    for (int i = 0; i < 32; i += 8)
        out[(size_t)(nb + ty + i) * 512 + kb + tx] = f2bf(tile[tx][ty + i]);
}

__global__ __launch_bounds__(256) void k_tr_wet(const float* __restrict__ We,
                                                ushort* __restrict__ out) {
    __shared__ float tile[32][33];
    int nb = blockIdx.x * 32, kb = blockIdx.y * 32;
    int tx = threadIdx.x & 31, ty = threadIdx.x >> 5;
    for (int i = 0; i < 32; i += 8) {
        int k = kb + ty + i, n = nb + tx;
        tile[ty + i][tx] = We[(size_t)k * ATTD + n];
    }
    __syncthreads();
    for (int i = 0; i < 32; i += 8)
        out[(size_t)(nb + ty + i) * ENCD + kb + tx] = f2bf(tile[tx][ty + i]);
}

// ---------------- one-time: att1 = enc @ We + be  (MFMA, bf16 out) ----------------
// block: 128x128 tile, 4 waves in 2x2; wave: 64x64 (4x4 16x16 frags), K=2048
__global__ __launch_bounds__(256) void k_att1(
        const float* __restrict__ enc, const ushort* __restrict__ WeT,
        const float* __restrict__ be, ushort* __restrict__ att1b) {
    int w = threadIdx.x >> 6, l = threadIdx.x & 63;
    int wr = w >> 1, wc = w & 1;
    int m0 = blockIdx.x * 128 + wr * 64;
    int n0 = blockIdx.y * 128 + wc * 64;
    int ml = l & 15, kg = l >> 4;
    const float*  aBase = enc + (size_t)(m0 + ml) * ENCD + kg * 8;
    const ushort* bBase = WeT + (size_t)(n0 + ml) * ENCD + kg * 8;
    f32x4 acc[4][4] = {};
    for (int k0 = 0; k0 < ENCD; k0 += 32) {
        bf16x8 bfr[4], afr[4];
#pragma unroll
        for (int nf = 0; nf < 4; ++nf)
            bfr[nf] = *(const bf16x8*)(bBase + (size_t)nf * 16 * ENCD + k0);
#pragma unroll
        for (int mf = 0; mf < 4; ++mf) {
            const float* ap = aBase + (size_t)mf * 16 * ENCD + k0;
            float4 f0 = *(const float4*)ap;
            float4 f1 = *(const float4*)(ap + 4);
            bf16x8 a;
            a[0] = f2bf(f0.x); a[1] = f2bf(f0.y); a[2] = f2bf(f0.z); a[3] = f2bf(f0.w);
            a[4] = f2bf(f1.x); a[5] = f2bf(f1.y); a[6] = f2bf(f1.z); a[7] = f2bf(f1.w);
            afr[mf] = a;
        }
#pragma unroll
        for (int mf = 0; mf < 4; ++mf)
#pragma unroll
            for (int nf = 0; nf < 4; ++nf)
                acc[mf][nf] = __builtin_amdgcn_mfma_f32_16x16x32_bf16(afr[mf], bfr[nf], acc[mf][nf], 0, 0, 0);
    }
#pragma unroll
    for (int mf = 0; mf < 4; ++mf)
#pragma unroll
        for (int nf = 0; nf < 4; ++nf) {
            int col = n0 + nf * 16 + ml;
            float bias = be[col];
#pragma unroll
            for (int r = 0; r < 4; ++r) {
                int row = m0 + mf * 16 + kg * 4 + r;
                att1b[(size_t)row * ATTD + col] = f2bf(acc[mf][nf][r] + bias);
            }
        }
}

// ---------------- per-step fused h-GEMM: pred(t) for h_new AND pre(t+1) ----------------
// M=64 (batch), K=512. pred blocks: N-tile of WfcT; pre blocks: N-tile of BpreT.
__global__ __launch_bounds__(256) void k_hgemm(
        const ushort* __restrict__ hbf, const ushort* __restrict__ WfcT,
        const float* __restrict__ bfc, const ushort* __restrict__ BpreT,
        const float* __restrict__ bd, const float* __restrict__ bfb,
        const int* __restrict__ lens, float* __restrict__ pred,
        float* __restrict__ att2, float* __restrict__ gate,
        int pred_t, int npred) {
    int blk = blockIdx.x;
    int w = threadIdx.x >> 6, l = threadIdx.x & 63;
    int m = l & 15, kg = l >> 4;
    bool isPred = blk < npred;
    int n0 = (isPred ? blk * 64 : (blk - npred) * 64) + w * 16 + m;
    const ushort* b0 = (isPred ? WfcT : BpreT) + (size_t)n0 * 512 + kg * 8;
    const ushort* a0 = hbf + (size_t)m * 512 + kg * 8;
    f32x4 acc[4] = {};
#pragma unroll 4
    for (int k0 = 0; k0 < 512; k0 += 32) {
        bf16x8 bfr = *(const bf16x8*)(b0 + k0);
#pragma unroll
        for (int mf = 0; mf < 4; ++mf) {
            bf16x8 afr = *(const bf16x8*)(a0 + mf * 16 * 512 + k0);
            acc[mf] = __builtin_amdgcn_mfma_f32_16x16x32_bf16(afr, bfr, acc[mf], 0, 0, 0);
        }
    }
    if (isPred) {
        if (n0 < NVOCAB) {
            float bias = bfc[n0];
#pragma unroll
            for (int mf = 0; mf < 4; ++mf)
#pragma unroll
                for (int r = 0; r < 4; ++r) {
                    int b = mf * 16 + kg * 4 + r;
                    bool act = pred_t < lens[b] - 1;
                    pred[((size_t)b * TSTEPS + pred_t) * NVOCAB + n0] = act ? acc[mf][r] + bias : 0.f;
                }
        }
    } else if (n0 < ATTD) {
        float bias = bd[n0];
#pragma unroll
        for (int mf = 0; mf < 4; ++mf)
#pragma unroll
            for (int r = 0; r < 4; ++r) {
                int b = mf * 16 + kg * 4 + r;
                att2[(size_t)b * ATTD + n0] = acc[mf][r] + bias;
            }
    } else {
        int e = n0 - ATTD;
        float bias = bfb[e];
#pragma unroll
        for (int mf = 0; mf < 4; ++mf)
#pragma unroll
            for (int r = 0; r < 4; ++r) {
                int b = mf * 16 + kg * 4 + r;
                float v = acc[mf][r] + bias;
                gate[(size_t)b * ENCD + e] = 1.f / (1.f + __expf(-v));
            }
    }
}

// ---------------- per-step: attention scores + softmax + context + X build ----------------
__global__ __launch_bounds__(512) void k_step_attn(
        const ushort* __restrict__ att1b, const float* __restrict__ att2,
        const float* __restrict__ gate, const ushort* __restrict__ hbf,
        const float* __restrict__ enc, const float* __restrict__ emb,
        const int* __restrict__ caps, const int* __restrict__ lens,
        const float* __restrict__ vatt, const float* __restrict__ bv,
        ushort* __restrict__ X, float* __restrict__ alpha_out, int t) {
    int b = blockIdx.x;
    __shared__ float a2[ATTD];
    __shared__ float vv[ATTD];
    __shared__ float ev[NPIX];
    __shared__ float inv_s;
    int tid = threadIdx.x;
    if (tid < ATTD) { a2[tid] = att2[(size_t)b * ATTD + tid]; vv[tid] = vatt[tid]; }
    __syncthreads();
    int wid = tid >> 6, lane = tid & 63;
    for (int p = wid; p < NPIX; p += 8) {
        const ushort* r = att1b + ((size_t)b * NPIX + p) * ATTD;
        float s = 0.f;
        for (int k = lane; k < ATTD; k += 64)
            s += fmaxf(bf2f(r[k]) + a2[k], 0.f) * vv[k];
        for (int off = 32; off > 0; off >>= 1) s += __shfl_down(s, off);
        if (lane == 0) ev[p] = s + bv[0];
    }
    __syncthreads();
    if (wid == 0) {
        float mx = -1e30f;
        for (int p = lane; p < NPIX; p += 64) mx = fmaxf(mx, ev[p]);
        for (int off = 32; off > 0; off >>= 1) mx = fmaxf(mx, __shfl_down(mx, off));
        mx = __shfl(mx, 0);
        float s = 0.f;
        for (int p = lane; p < NPIX; p += 64) {
            float e_ = __expf(ev[p] - mx);
            ev[p] = e_;
            s += e_;
        }
        for (int off = 32; off > 0; off >>= 1) s += __shfl_down(s, off);
        if (lane == 0) inv_s = 1.0f / s;
    }
    __syncthreads();
    float inv = inv_s;
    bool active = t < (lens[b] - 1);
    for (int p = tid; p < NPIX; p += 512)
        alpha_out[((size_t)b * TSTEPS + t) * NPIX + p] = active ? ev[p] * inv : 0.f;
    // context: thread handles 4 e-dims via float4
    {
        const float4* encb = (const float4*)(enc + (size_t)b * NPIX * ENCD);
        float s0 = 0.f, s1 = 0.f, s2 = 0.f, s3 = 0.f;
        for (int p = 0; p < NPIX; ++p) {
            float4 v = encb[(size_t)p * (ENCD / 4) + tid];
            float al = ev[p];
            s0 += al * v.x; s1 += al * v.y; s2 += al * v.z; s3 += al * v.w;
        }
        const float4 g = *(const float4*)(gate + (size_t)b * ENCD + tid * 4);
        ushort* Xc = X + (size_t)b * KX + EMBD + tid * 4;
        Xc[0] = f2bf(s0 * inv * g.x);
        Xc[1] = f2bf(s1 * inv * g.y);
        Xc[2] = f2bf(s2 * inv * g.z);
        Xc[3] = f2bf(s3 * inv * g.w);
    }
    // emb + h parts
    if (tid < EMBD) {
        int tok = caps[b * 25 + t];
        X[(size_t)b * KX + tid] = f2bf(emb[(size_t)tok * EMBD + tid]);
        X[(size_t)b * KX + EMBD + ENCD + tid] = hbf[(size_t)b * DECD + tid];
    }
}

// ---------------- per-step: gates GEMM (MFMA) + fused LSTM pointwise ----------------
// block g (0..31): dims d = g*16..g*16+15, wave w = gate index (i,f,g,o)
__global__ __launch_bounds__(256) void k_gates(
        const ushort* __restrict__ X, const ushort* __restrict__ WTj,
        const float* __restrict__ bih, const float* __restrict__ bhh,
        const int* __restrict__ lens, float* __restrict__ c,
        ushort* __restrict__ hbf, int t) {
    __shared__ float gt[64][65];
    int g = blockIdx.x;
    int w = threadIdx.x >> 6, l = threadIdx.x & 63;
    int m = l & 15, kg = l >> 4;
    int j = w * 512 + g * 16 + m;
    const ushort* a0 = X + (size_t)m * KX + kg * 8;
    const ushort* b0 = WTj + (size_t)j * KX + kg * 8;
    f32x4 acc[4] = {};
#pragma unroll 4
    for (int k0 = 0; k0 < KX; k0 += 32) {
        bf16x8 bfr = *(const bf16x8*)(b0 + k0);
#pragma unroll
        for (int mf = 0; mf < 4; ++mf) {
            bf16x8 afr = *(const bf16x8*)(a0 + mf * 16 * KX + k0);
            acc[mf] = __builtin_amdgcn_mfma_f32_16x16x32_bf16(afr, bfr, acc[mf], 0, 0, 0);
        }
    }
#pragma unroll
    for (int mf = 0; mf < 4; ++mf)
#pragma unroll
        for (int r = 0; r < 4; ++r)
            gt[mf * 16 + kg * 4 + r][w * 16 + m] = acc[mf][r];
    __syncthreads();
    for (int idx = threadIdx.x; idx < 1024; idx += 256) {
        int b = idx >> 4, r = idx & 15;
        int d = g * 16 + r;
        if (t < lens[b] - 1) {
            float gi = gt[b][r]      + bih[d]          + bhh[d];
            float gf = gt[b][16 + r] + bih[512 + d]    + bhh[512 + d];
            float gg = gt[b][32 + r] + bih[1024 + d]   + bhh[1024 + d];
            float go = gt[b][48 + r] + bih[1536 + d]   + bhh[1536 + d];
            float cc = c[(size_t)b * DECD + d];
            float si = 1.f / (1.f + __expf(-gi));
            float sf = 1.f / (1.f + __expf(-gf));
            float so = 1.f / (1.f + __expf(-go));
            float cn = sf * cc + si * tanhf(gg);
            float hn = so * tanhf(cn);
            c[(size_t)b * DECD + d] = cn;
            hbf[(size_t)b * DECD + d] = f2bf(hn);
        }
    }
}

extern "C" void kernel_launch(void* const* d_in, const int* in_sizes, int n_in,
                              void* d_out, int out_size, void* d_ws, size_t ws_size,
                              hipStream_t stream) {
    const float* enc  = (const float*)d_in[0];
    const int*   caps = (const int*)d_in[1];
    const int*   lens = (const int*)d_in[2];
    const float* emb  = (const float*)d_in[3];
    const float* We   = (const float*)d_in[4];
    const float* be   = (const float*)d_in[5];
    const float* Wd   = (const float*)d_in[6];
    const float* bd   = (const float*)d_in[7];
    const float* vatt = (const float*)d_in[8];
    const float* bv   = (const float*)d_in[9];
    const float* Wih  = (const float*)d_in[10];
    const float* bih  = (const float*)d_in[11];
    const float* Whh  = (const float*)d_in[12];
    const float* bhh  = (const float*)d_in[13];
    const float* Winh = (const float*)d_in[14];
    const float* binh = (const float*)d_in[15];
    const float* Winc = (const float*)d_in[16];
    const float* binc = (const float*)d_in[17];
    const float* Wfb  = (const float*)d_in[18];
    const float* bfb  = (const float*)d_in[19];
    const float* Wfc  = (const float*)d_in[20];
    const float* bfc  = (const float*)d_in[21];

    float* out       = (float*)d_out;
    float* pred_out  = out;
    float* cap_out   = out + 15360000;
    float* len_out   = out + 15361600;
    float* alpha_out = out + 15361664;

    char* p = (char*)d_ws;
    ushort* att1b = (ushort*)p; p += (size_t)12544 * 512 * 2;
    ushort* WTj   = (ushort*)p; p += (size_t)2048 * 3072 * 2;
    ushort* WfcT  = (ushort*)p; p += (size_t)10048 * 512 * 2;
    ushort* BpreT = (ushort*)p; p += (size_t)2560 * 512 * 2;
    ushort* WeT   = (ushort*)p; p += (size_t)512 * 2048 * 2;
    ushort* X     = (ushort*)p; p += (size_t)64 * 3072 * 2;
    ushort* hbf   = (ushort*)p; p += (size_t)64 * 512 * 2;
    float* att2   = (float*)p;  p += (size_t)64 * 512 * 4;
    float* gate   = (float*)p;  p += (size_t)64 * 2048 * 4;
    float* c      = (float*)p;  p += (size_t)64 * 512 * 4;
    float* mean   = (float*)p;  p += (size_t)64 * 2048 * 4;

    k_meta<<<7, 256, 0, stream>>>(caps, lens, cap_out, len_out);
    k_mean<<<dim3(BATCH, 8), 256, 0, stream>>>(enc, mean);
    k_init_hc<<<dim3(16, 4), 256, 0, stream>>>(mean, Winh, binh, Winc, binc, hbf, c);
    k_cp_wtj<<<2048, 256, 0, stream>>>(Wih, Whh, WTj);
    k_tr_bpre<<<dim3(80, 16), 256, 0, stream>>>(Wd, Wfb, BpreT);
    k_tr_wfct<<<dim3(314, 16), 256, 0, stream>>>(Wfc, WfcT);
    k_tr_wet<<<dim3(16, 64), 256, 0, stream>>>(We, WeT);
    k_att1<<<dim3(98, 4), 256, 0, stream>>>(enc, WeT, be, att1b);

    // pre for t=0 (no pred yet)
    k_hgemm<<<40, 256, 0, stream>>>(hbf, WfcT, bfc, BpreT, bd, bfb, lens,
                                    pred_out, att2, gate, -1, 0);
    for (int t = 0; t < TSTEPS; ++t) {
        k_step_attn<<<BATCH, 512, 0, stream>>>(att1b, att2, gate, hbf, enc, emb,
                                               caps, lens, vatt, bv, X, alpha_out, t);
        k_gates<<<32, 256, 0, stream>>>(X, WTj, bih, bhh, lens, c, hbf, t);
        if (t < TSTEPS - 1) {
            // pred for step t (uses h_{t+1}) fused with pre for step t+1
            k_hgemm<<<197, 256, 0, stream>>>(hbf, WfcT, bfc, BpreT, bd, bfb, lens,
                                             pred_out, att2, gate, t, 157);
        } else {
            k_hgemm<<<157, 256, 0, stream>>>(hbf, WfcT, bfc, BpreT, bd, bfb, lens,
                                             pred_out, att2, gate, t, 157);
        }
    }
}